// Round 1
// baseline (1661.823 us; speedup 1.0000x reference)
//
#include <hip/hip_runtime.h>

#define B_ 2
#define S_ 2048
#define H_ 4096
#define NH_ 32
#define HD_ 128
#define LOG2E 1.44269504088896340736f

typedef unsigned short u16;
typedef __bf16 bf16x8 __attribute__((ext_vector_type(8)));
typedef float floatx4 __attribute__((ext_vector_type(4)));

__device__ __forceinline__ u16 f2bf(float f) {
  union { float f; unsigned u; } v;
  v.f = f;
  unsigned r = v.u + 0x7FFFu + ((v.u >> 16) & 1u);
  return (u16)(r >> 16);
}

// ---------------- cast fp32 -> bf16, vectorized ----------------
__global__ __launch_bounds__(256) void cast_f32_bf16(const float* __restrict__ in,
                                                     u16* __restrict__ out, int n4) {
  int i = blockIdx.x * 256 + threadIdx.x;
  if (i >= n4) return;
  float4 f = reinterpret_cast<const float4*>(in)[i];
  ushort4 o;
  o.x = f2bf(f.x); o.y = f2bf(f.y); o.z = f2bf(f.z); o.w = f2bf(f.w);
  reinterpret_cast<ushort4*>(out)[i] = o;
}

// ---------------- GEMM: C[m][n] = sum_k A[m][k] * B[n][k]  (both K-contiguous)
// 128x128 block tile, BK=32, 256 threads = 4 waves, each wave 64x64 (4x4 MFMA tiles)
// EPI=0: QKV epilogue (bias, scatter Q/K/Vt as bf16, Q scaled by 1/sqrt(HD))
// EPI=1: dense epilogue (bias + residual, fp32 out)
#define LSTR 40  // padded LDS row stride (elements); 80B rows, 16B aligned, 2-way max conflict

template<int EPI>
__global__ __launch_bounds__(256) void gemm_bt(
    const u16* __restrict__ A, const u16* __restrict__ Bm, int K,
    const float* __restrict__ bias, const float* __restrict__ resid,
    float* __restrict__ outf,
    u16* __restrict__ qo, u16* __restrict__ ko, u16* __restrict__ vto) {
  __shared__ __align__(16) u16 sA[128 * LSTR];
  __shared__ __align__(16) u16 sB[128 * LSTR];
  const int tid  = threadIdx.x;
  const int wave = tid >> 6, lane = tid & 63;
  const int lrow = lane & 15, quad = lane >> 4;
  const int wm = (wave >> 1) * 64, wn = (wave & 1) * 64;
  const int m0 = blockIdx.y * 128, n0 = blockIdx.x * 128;

  const floatx4 zf = {0.f, 0.f, 0.f, 0.f};
  floatx4 acc[4][4];
#pragma unroll
  for (int i = 0; i < 4; ++i)
#pragma unroll
    for (int j = 0; j < 4; ++j) acc[i][j] = zf;

  for (int k0 = 0; k0 < K; k0 += 32) {
    __syncthreads();
#pragma unroll
    for (int rr = 0; rr < 2; ++rr) {
      int flat = rr * 256 + tid;          // 0..511
      int row = flat >> 2, c = flat & 3;  // 128 rows x 4 chunks of 8 elems
      *(uint4*)&sA[row * LSTR + c * 8] = *(const uint4*)&A[(m0 + row) * K + k0 + c * 8];
      *(uint4*)&sB[row * LSTR + c * 8] = *(const uint4*)&Bm[(n0 + row) * K + k0 + c * 8];
    }
    __syncthreads();
    bf16x8 af[4], bf[4];
#pragma unroll
    for (int mi = 0; mi < 4; ++mi)
      af[mi] = *(const bf16x8*)&sA[(wm + mi * 16 + lrow) * LSTR + quad * 8];
#pragma unroll
    for (int ni = 0; ni < 4; ++ni)
      bf[ni] = *(const bf16x8*)&sB[(wn + ni * 16 + lrow) * LSTR + quad * 8];
#pragma unroll
    for (int mi = 0; mi < 4; ++mi)
#pragma unroll
      for (int ni = 0; ni < 4; ++ni)
        acc[mi][ni] = __builtin_amdgcn_mfma_f32_16x16x32_bf16(af[mi], bf[ni], acc[mi][ni], 0, 0, 0);
  }

  // epilogue — C/D layout: col = lane&15 (n), row = quad*4 + reg (m)
#pragma unroll
  for (int mi = 0; mi < 4; ++mi)
#pragma unroll
    for (int ni = 0; ni < 4; ++ni)
#pragma unroll
      for (int r = 0; r < 4; ++r) {
        int m = m0 + wm + mi * 16 + quad * 4 + r;
        int n = n0 + wn + ni * 16 + lrow;
        float v = acc[mi][ni][r] + bias[n];
        if (EPI == 0) {
          int b = m >> 11, s = m & (S_ - 1);
          int nh = n / (3 * HD_);
          int rem = n - nh * 3 * HD_;
          int which = rem >> 7, d = rem & (HD_ - 1);
          int bh = b * NH_ + nh;
          if (which == 0)      qo[(bh * S_ + s) * HD_ + d] = f2bf(v * 0.08838834764831845f);
          else if (which == 1) ko[(bh * S_ + s) * HD_ + d] = f2bf(v);
          else                 vto[(bh * HD_ + d) * S_ + s] = f2bf(v);
        } else {
          int idx = m * H_ + n;
          outf[idx] = v + resid[idx];
        }
      }
}

// ---------------- flash attention (causal + alibi) ----------------
// grid: (S/64, B*NH). block: 256 = 4 waves; wave w owns q rows qbase + w*16 .. +15.
// KV tiles of 64 staged in LDS; online softmax; P -> LDS -> A-fragment for PV.
#define SKSTR 136  // 64 x (128+8) bf16
#define SVSTR 72   // 128 x (64+8) bf16
#define SPSTR 72   // 16 x (64+8) bf16 per wave

__global__ __launch_bounds__(256) void attn_kernel(
    const u16* __restrict__ Qb, const u16* __restrict__ Kb,
    const u16* __restrict__ Vt, const float* __restrict__ alibi,
    u16* __restrict__ ctx) {
  __shared__ __align__(16) u16 sK[64 * SKSTR];
  __shared__ __align__(16) u16 sV[128 * SVSTR];
  __shared__ __align__(16) u16 sP[4 * 16 * SPSTR];
  const int tid  = threadIdx.x;
  const int wave = tid >> 6, lane = tid & 63;
  const int lrow = lane & 15, quad = lane >> 4;
  const int qt = blockIdx.x, bh = blockIdx.y;
  const int qbase = qt * 64;
  const int qrow0 = qbase + wave * 16 + quad * 4;

  const floatx4 zf = {0.f, 0.f, 0.f, 0.f};

  // Q fragments: A[m=lane&15][k=quad*8+j], 4 chunks of k=32 cover d=0..127
  bf16x8 aq[4];
  {
    const u16* qptr = Qb + (bh * S_ + qbase + wave * 16 + lrow) * HD_;
#pragma unroll
    for (int kc = 0; kc < 4; ++kc) aq[kc] = *(const bf16x8*)(qptr + kc * 32 + quad * 8);
  }

  floatx4 o[8];
#pragma unroll
  for (int di = 0; di < 8; ++di) o[di] = zf;
  float m_r[4] = {-1e30f, -1e30f, -1e30f, -1e30f};
  float l_r[4] = {0.f, 0.f, 0.f, 0.f};
  u16* sp = &sP[wave * 16 * SPSTR];

  for (int t = 0; t <= qt; ++t) {
    const int kv0 = t * 64;
    __syncthreads();  // previous iteration's LDS reads done
#pragma unroll
    for (int rr = 0; rr < 4; ++rr) {
      int flat = rr * 256 + tid;  // 0..1023
      {
        int row = flat >> 4, c = flat & 15;  // K tile: 64 rows x 16 chunks
        *(uint4*)&sK[row * SKSTR + c * 8] =
            *(const uint4*)&Kb[(bh * S_ + kv0 + row) * HD_ + c * 8];
      }
      {
        int row = flat >> 3, c = flat & 7;   // Vt tile: 128 rows x 8 chunks
        *(uint4*)&sV[row * SVSTR + c * 8] =
            *(const uint4*)&Vt[(bh * HD_ + row) * S_ + kv0 + c * 8];
      }
    }
    __syncthreads();

    // scores: S[q=16][kv=64], Q pre-scaled by 1/sqrt(HD)
    floatx4 sc[4];
#pragma unroll
    for (int ni = 0; ni < 4; ++ni) {
      floatx4 a = zf;
#pragma unroll
      for (int kc = 0; kc < 4; ++kc) {
        bf16x8 bfrag = *(const bf16x8*)&sK[(ni * 16 + lrow) * SKSTR + kc * 32 + quad * 8];
        a = __builtin_amdgcn_mfma_f32_16x16x32_bf16(aq[kc], bfrag, a, 0, 0, 0);
      }
      sc[ni] = a;
    }

    float al[4];
#pragma unroll
    for (int ni = 0; ni < 4; ++ni) al[ni] = alibi[bh * S_ + kv0 + ni * 16 + lrow];
    const bool diag = (t == qt);

    float p[4][4], alpha[4];
#pragma unroll
    for (int r = 0; r < 4; ++r) {
      float mx = -1e30f;
#pragma unroll
      for (int ni = 0; ni < 4; ++ni) {
        float scv = sc[ni][r] + al[ni];
        if (diag && (kv0 + ni * 16 + lrow) > (qrow0 + r)) scv = -1e30f;  // causal mask
        p[ni][r] = scv;
        mx = fmaxf(mx, scv);
      }
#pragma unroll
      for (int off = 1; off < 16; off <<= 1) mx = fmaxf(mx, __shfl_xor(mx, off));
      float mn = fmaxf(m_r[r], mx);
      float a_ = exp2f((m_r[r] - mn) * LOG2E);
      float s_ = 0.f;
#pragma unroll
      for (int ni = 0; ni < 4; ++ni) {
        float pv = exp2f((p[ni][r] - mn) * LOG2E);
        p[ni][r] = pv;
        s_ += pv;
      }
#pragma unroll
      for (int off = 1; off < 16; off <<= 1) s_ += __shfl_xor(s_, off);
      l_r[r] = l_r[r] * a_ + s_;
      m_r[r] = mn;
      alpha[r] = a_;
    }
#pragma unroll
    for (int di = 0; di < 8; ++di)
#pragma unroll
      for (int r = 0; r < 4; ++r) o[di][r] *= alpha[r];

    // P: C-layout -> LDS (bf16) -> A-fragment layout
#pragma unroll
    for (int ni = 0; ni < 4; ++ni)
#pragma unroll
      for (int r = 0; r < 4; ++r)
        sp[(quad * 4 + r) * SPSTR + ni * 16 + lrow] = f2bf(p[ni][r]);
    __syncthreads();

    // PV: O[q=16][d=128] += P[16][64] * Vt[d][kv]
#pragma unroll
    for (int kc = 0; kc < 2; ++kc) {
      bf16x8 afrag = *(const bf16x8*)&sp[lrow * SPSTR + kc * 32 + quad * 8];
#pragma unroll
      for (int di = 0; di < 8; ++di) {
        bf16x8 bfrag = *(const bf16x8*)&sV[(di * 16 + lrow) * SVSTR + kc * 32 + quad * 8];
        o[di] = __builtin_amdgcn_mfma_f32_16x16x32_bf16(afrag, bfrag, o[di], 0, 0, 0);
      }
    }
  }

  // epilogue: ctx[b][q][nh*128 + d] bf16
  const int b = bh >> 5, nh = bh & (NH_ - 1);
#pragma unroll
  for (int di = 0; di < 8; ++di)
#pragma unroll
    for (int r = 0; r < 4; ++r) {
      int q = qrow0 + r;
      float v = o[di][r] / l_r[r];
      ctx[(b * S_ + q) * H_ + nh * HD_ + di * 16 + lrow] = f2bf(v);
    }
}

// ---------------- launch ----------------
extern "C" void kernel_launch(void* const* d_in, const int* in_sizes, int n_in,
                              void* d_out, int out_size, void* d_ws, size_t ws_size,
                              hipStream_t stream) {
  const float* hs    = (const float*)d_in[0];
  const float* resid = (const float*)d_in[1];
  const float* alibi = (const float*)d_in[2];
  // d_in[3] = attention_mask: deterministic causal triu -> applied analytically
  const float* Wqkv  = (const float*)d_in[4];
  const float* bqkv  = (const float*)d_in[5];
  const float* Wd    = (const float*)d_in[6];
  const float* bd    = (const float*)d_in[7];
  float* out = (float*)d_out;

  u16* ws = (u16*)d_ws;
  // layout (elements): [0, 16.7M) hs_bf16 / later ctx_bf16
  //                    [16.7M, 67.1M) Wqkv_bf16 / later Wd_bf16
  //                    [67.1M..) Q, K, Vt (16.7M each)  => 224 MB total
  u16* hs_bf  = ws;
  u16* ctx_bf = ws;                 // alias: hs_bf dead after QKV GEMM
  u16* w_bf   = ws + 16777216;
  u16* Qb     = ws + 67108864;
  u16* Kb     = ws + 83886080;
  u16* Vtb    = ws + 100663296;

  cast_f32_bf16<<<16384, 256, 0, stream>>>(hs, hs_bf, 4194304);
  cast_f32_bf16<<<49152, 256, 0, stream>>>(Wqkv, w_bf, 12582912);
  gemm_bt<0><<<dim3(96, 32), 256, 0, stream>>>(hs_bf, w_bf, 4096, bqkv,
                                               nullptr, nullptr, Qb, Kb, Vtb);
  attn_kernel<<<dim3(32, 64), 256, 0, stream>>>(Qb, Kb, Vtb, alibi, ctx_bf);
  cast_f32_bf16<<<16384, 256, 0, stream>>>(Wd, w_bf, 4194304);
  gemm_bt<1><<<dim3(32, 32), 256, 0, stream>>>(ctx_bf, w_bf, 4096, bd,
                                               resid, out, nullptr, nullptr, nullptr);
}

// Round 2
// 1599.705 us; speedup vs baseline: 1.0388x; 1.0388x over previous
//
#include <hip/hip_runtime.h>

#define B_ 2
#define S_ 2048
#define H_ 4096
#define NH_ 32
#define HD_ 128
#define LOG2E 1.44269504088896340736f

typedef unsigned short u16;
typedef __bf16 bf16x8 __attribute__((ext_vector_type(8)));
typedef float floatx4 __attribute__((ext_vector_type(4)));

__device__ __forceinline__ u16 f2bf(float f) {
  union { float f; unsigned u; } v;
  v.f = f;
  unsigned r = v.u + 0x7FFFu + ((v.u >> 16) & 1u);
  return (u16)(r >> 16);
}

// async global->LDS DMA, 16B per lane; LDS dest = wave-uniform base + lane*16
__device__ __forceinline__ void dma16(const u16* g, u16* l) {
  __builtin_amdgcn_global_load_lds(
      (const __attribute__((address_space(1))) void*)g,
      (__attribute__((address_space(3))) void*)l, 16, 0, 0);
}

// ---------------- cast fp32 -> bf16, vectorized ----------------
__global__ __launch_bounds__(256) void cast_f32_bf16(const float* __restrict__ in,
                                                     u16* __restrict__ out, int n4) {
  int i = blockIdx.x * 256 + threadIdx.x;
  if (i >= n4) return;
  float4 f = reinterpret_cast<const float4*>(in)[i];
  ushort4 o;
  o.x = f2bf(f.x); o.y = f2bf(f.y); o.z = f2bf(f.z); o.w = f2bf(f.w);
  reinterpret_cast<ushort4*>(out)[i] = o;
}

// ---------------- GEMM: C[m][n] = sum_k A[m][k]*B[n][k] (both K-contiguous)
// 128x128 tile, BK=32, 4 waves, each wave 64x64 via 4x4 mfma_16x16x32_bf16.
// Staging: global_load_lds width=16 into unpadded LDS; XOR swizzle on 128B
// lines (slot s of line L holds sub-chunk s^(L&7)) -> 2-way max bank aliasing
// on both DMA writes and b128 fragment reads.
template<int EPI>
__global__ __launch_bounds__(256) void gemm_bt(
    const u16* __restrict__ A, const u16* __restrict__ Bm, int K,
    const float* __restrict__ bias, const float* __restrict__ resid,
    float* __restrict__ outf,
    u16* __restrict__ qo, u16* __restrict__ ko, u16* __restrict__ vto) {
  __shared__ __align__(16) u16 sA[128 * 32];   // 8KB: 64 lines x 128B
  __shared__ __align__(16) u16 sB[128 * 32];
  const int tid  = threadIdx.x;
  const int wave = tid >> 6, lane = tid & 63;
  const int lrow = lane & 15, quad = lane >> 4;
  const int wm = (wave >> 1) * 64, wn = (wave & 1) * 64;
  const int m0 = blockIdx.y * 128, n0 = blockIdx.x * 128;

  // staging: wave w, jj in {0,1} covers lines Lb=w*16+jj*8 .. +7 (1KB each)
  // lane: L = Lb + (lane>>3), slot s = lane&7, s' = s^(L&7),
  //       global row = 2L + (s'>>2), k-chunk = (s'&3)*8
  const u16* gA[2]; const u16* gB[2];
#pragma unroll
  for (int jj = 0; jj < 2; ++jj) {
    int L  = wave * 16 + jj * 8 + (lane >> 3);
    int sp = (lane & 7) ^ (L & 7);
    int row = 2 * L + (sp >> 2), kc = (sp & 3) * 8;
    gA[jj] = A + (size_t)(m0 + row) * K + kc;
    gB[jj] = Bm + (size_t)(n0 + row) * K + kc;
  }

  // fragment-read swizzle: want (row r, k-chunk quad) -> line r>>1,
  // slot (((r&1)<<2)|quad) ^ ((r>>1)&7); lane-constant part:
  const int ssw  = (((lrow & 1) << 2) | quad) ^ ((lrow >> 1) & 7);
  const int aoff = ((wm + lrow) >> 1) * 64 + ssw * 8;  // u16 elements
  const int boff = ((wn + lrow) >> 1) * 64 + ssw * 8;

  const floatx4 zf = {0.f, 0.f, 0.f, 0.f};
  floatx4 acc[4][4];
#pragma unroll
  for (int i = 0; i < 4; ++i)
#pragma unroll
    for (int j = 0; j < 4; ++j) acc[i][j] = zf;

  for (int k0 = 0; k0 < K; k0 += 32) {
    __syncthreads();  // previous iteration's LDS reads done
#pragma unroll
    for (int jj = 0; jj < 2; ++jj) {
      dma16(gA[jj], &sA[(wave * 2 + jj) * 512]);
      dma16(gB[jj], &sB[(wave * 2 + jj) * 512]);
      gA[jj] += 32; gB[jj] += 32;
    }
    __syncthreads();  // drains vmcnt(0): DMA complete

    bf16x8 af[4], bf[4];
#pragma unroll
    for (int mi = 0; mi < 4; ++mi) af[mi] = *(const bf16x8*)&sA[aoff + mi * 512];
#pragma unroll
    for (int ni = 0; ni < 4; ++ni) bf[ni] = *(const bf16x8*)&sB[boff + ni * 512];
#pragma unroll
    for (int mi = 0; mi < 4; ++mi)
#pragma unroll
      for (int ni = 0; ni < 4; ++ni)
        acc[mi][ni] = __builtin_amdgcn_mfma_f32_16x16x32_bf16(af[mi], bf[ni], acc[mi][ni], 0, 0, 0);
  }

  // epilogue — C/D layout: col = lane&15 (n), row = quad*4 + reg (m)
#pragma unroll
  for (int mi = 0; mi < 4; ++mi)
#pragma unroll
    for (int ni = 0; ni < 4; ++ni)
#pragma unroll
      for (int r = 0; r < 4; ++r) {
        int m = m0 + wm + mi * 16 + quad * 4 + r;
        int n = n0 + wn + ni * 16 + lrow;
        float v = acc[mi][ni][r] + bias[n];
        if (EPI == 0) {
          int b = m >> 11, s = m & (S_ - 1);
          int nh = n / (3 * HD_);
          int rem = n - nh * 3 * HD_;
          int which = rem >> 7, d = rem & (HD_ - 1);
          int bh = b * NH_ + nh;
          if (which == 0)      qo[(bh * S_ + s) * HD_ + d] = f2bf(v * 0.08838834764831845f);
          else if (which == 1) ko[(bh * S_ + s) * HD_ + d] = f2bf(v);
          else                 vto[(bh * HD_ + d) * S_ + s] = f2bf(v);
        } else {
          int idx = m * H_ + n;
          outf[idx] = v + resid[idx];
        }
      }
}

// ---------------- flash attention (causal + alibi) ----------------
// grid: (S/64, B*NH). block: 256 = 4 waves; wave w owns q rows qbase + w*16 .. +15.
// KV tiles of 64 staged in LDS; online softmax; P -> LDS -> A-fragment for PV.
#define SKSTR 136  // 64 x (128+8) bf16
#define SVSTR 72   // 128 x (64+8) bf16
#define SPSTR 72   // 16 x (64+8) bf16 per wave

__global__ __launch_bounds__(256) void attn_kernel(
    const u16* __restrict__ Qb, const u16* __restrict__ Kb,
    const u16* __restrict__ Vt, const float* __restrict__ alibi,
    u16* __restrict__ ctx) {
  __shared__ __align__(16) u16 sK[64 * SKSTR];
  __shared__ __align__(16) u16 sV[128 * SVSTR];
  __shared__ __align__(16) u16 sP[4 * 16 * SPSTR];
  const int tid  = threadIdx.x;
  const int wave = tid >> 6, lane = tid & 63;
  const int lrow = lane & 15, quad = lane >> 4;
  const int qt = blockIdx.x, bh = blockIdx.y;
  const int qbase = qt * 64;
  const int qrow0 = qbase + wave * 16 + quad * 4;

  const floatx4 zf = {0.f, 0.f, 0.f, 0.f};

  // Q fragments: A[m=lane&15][k=quad*8+j], 4 chunks of k=32 cover d=0..127
  bf16x8 aq[4];
  {
    const u16* qptr = Qb + (bh * S_ + qbase + wave * 16 + lrow) * HD_;
#pragma unroll
    for (int kc = 0; kc < 4; ++kc) aq[kc] = *(const bf16x8*)(qptr + kc * 32 + quad * 8);
  }

  floatx4 o[8];
#pragma unroll
  for (int di = 0; di < 8; ++di) o[di] = zf;
  float m_r[4] = {-1e30f, -1e30f, -1e30f, -1e30f};
  float l_r[4] = {0.f, 0.f, 0.f, 0.f};
  u16* sp = &sP[wave * 16 * SPSTR];

  for (int t = 0; t <= qt; ++t) {
    const int kv0 = t * 64;
    __syncthreads();  // previous iteration's LDS reads done
#pragma unroll
    for (int rr = 0; rr < 4; ++rr) {
      int flat = rr * 256 + tid;  // 0..1023
      {
        int row = flat >> 4, c = flat & 15;  // K tile: 64 rows x 16 chunks
        *(uint4*)&sK[row * SKSTR + c * 8] =
            *(const uint4*)&Kb[(bh * S_ + kv0 + row) * HD_ + c * 8];
      }
      {
        int row = flat >> 3, c = flat & 7;   // Vt tile: 128 rows x 8 chunks
        *(uint4*)&sV[row * SVSTR + c * 8] =
            *(const uint4*)&Vt[(bh * HD_ + row) * S_ + kv0 + c * 8];
      }
    }
    __syncthreads();

    // scores: S[q=16][kv=64], Q pre-scaled by 1/sqrt(HD)
    floatx4 sc[4];
#pragma unroll
    for (int ni = 0; ni < 4; ++ni) {
      floatx4 a = zf;
#pragma unroll
      for (int kc = 0; kc < 4; ++kc) {
        bf16x8 bfrag = *(const bf16x8*)&sK[(ni * 16 + lrow) * SKSTR + kc * 32 + quad * 8];
        a = __builtin_amdgcn_mfma_f32_16x16x32_bf16(aq[kc], bfrag, a, 0, 0, 0);
      }
      sc[ni] = a;
    }

    float al[4];
#pragma unroll
    for (int ni = 0; ni < 4; ++ni) al[ni] = alibi[bh * S_ + kv0 + ni * 16 + lrow];
    const bool diag = (t == qt);

    float p[4][4], alpha[4];
#pragma unroll
    for (int r = 0; r < 4; ++r) {
      float mx = -1e30f;
#pragma unroll
      for (int ni = 0; ni < 4; ++ni) {
        float scv = sc[ni][r] + al[ni];
        if (diag && (kv0 + ni * 16 + lrow) > (qrow0 + r)) scv = -1e30f;  // causal mask
        p[ni][r] = scv;
        mx = fmaxf(mx, scv);
      }
#pragma unroll
      for (int off = 1; off < 16; off <<= 1) mx = fmaxf(mx, __shfl_xor(mx, off));
      float mn = fmaxf(m_r[r], mx);
      float a_ = exp2f((m_r[r] - mn) * LOG2E);
      float s_ = 0.f;
#pragma unroll
      for (int ni = 0; ni < 4; ++ni) {
        float pv = exp2f((p[ni][r] - mn) * LOG2E);
        p[ni][r] = pv;
        s_ += pv;
      }
#pragma unroll
      for (int off = 1; off < 16; off <<= 1) s_ += __shfl_xor(s_, off);
      l_r[r] = l_r[r] * a_ + s_;
      m_r[r] = mn;
      alpha[r] = a_;
    }
#pragma unroll
    for (int di = 0; di < 8; ++di)
#pragma unroll
      for (int r = 0; r < 4; ++r) o[di][r] *= alpha[r];

    // P: C-layout -> LDS (bf16) -> A-fragment layout
#pragma unroll
    for (int ni = 0; ni < 4; ++ni)
#pragma unroll
      for (int r = 0; r < 4; ++r)
        sp[(quad * 4 + r) * SPSTR + ni * 16 + lrow] = f2bf(p[ni][r]);
    __syncthreads();

    // PV: O[q=16][d=128] += P[16][64] * Vt[d][kv]
#pragma unroll
    for (int kc = 0; kc < 2; ++kc) {
      bf16x8 afrag = *(const bf16x8*)&sp[lrow * SPSTR + kc * 32 + quad * 8];
#pragma unroll
      for (int di = 0; di < 8; ++di) {
        bf16x8 bfrag = *(const bf16x8*)&sV[(di * 16 + lrow) * SVSTR + kc * 32 + quad * 8];
        o[di] = __builtin_amdgcn_mfma_f32_16x16x32_bf16(afrag, bfrag, o[di], 0, 0, 0);
      }
    }
  }

  // epilogue: ctx[b][q][nh*128 + d] bf16
  const int b = bh >> 5, nh = bh & (NH_ - 1);
#pragma unroll
  for (int di = 0; di < 8; ++di)
#pragma unroll
    for (int r = 0; r < 4; ++r) {
      int q = qrow0 + r;
      float v = o[di][r] / l_r[r];
      ctx[(b * S_ + q) * H_ + nh * HD_ + di * 16 + lrow] = f2bf(v);
    }
}

// ---------------- launch ----------------
extern "C" void kernel_launch(void* const* d_in, const int* in_sizes, int n_in,
                              void* d_out, int out_size, void* d_ws, size_t ws_size,
                              hipStream_t stream) {
  const float* hs    = (const float*)d_in[0];
  const float* resid = (const float*)d_in[1];
  const float* alibi = (const float*)d_in[2];
  // d_in[3] = attention_mask: deterministic causal triu -> applied analytically
  const float* Wqkv  = (const float*)d_in[4];
  const float* bqkv  = (const float*)d_in[5];
  const float* Wd    = (const float*)d_in[6];
  const float* bd    = (const float*)d_in[7];
  float* out = (float*)d_out;

  u16* ws = (u16*)d_ws;
  // layout (elements): [0, 16.7M) hs_bf16 / later ctx_bf16
  //                    [16.7M, 67.1M) Wqkv_bf16 / later Wd_bf16
  //                    [67.1M..) Q, K, Vt (16.7M each)  => 224 MB total
  u16* hs_bf  = ws;
  u16* ctx_bf = ws;                 // alias: hs_bf dead after QKV GEMM
  u16* w_bf   = ws + 16777216;
  u16* Qb     = ws + 67108864;
  u16* Kb     = ws + 83886080;
  u16* Vtb    = ws + 100663296;

  cast_f32_bf16<<<16384, 256, 0, stream>>>(hs, hs_bf, 4194304);
  cast_f32_bf16<<<49152, 256, 0, stream>>>(Wqkv, w_bf, 12582912);
  gemm_bt<0><<<dim3(96, 32), 256, 0, stream>>>(hs_bf, w_bf, 4096, bqkv,
                                               nullptr, nullptr, Qb, Kb, Vtb);
  attn_kernel<<<dim3(32, 64), 256, 0, stream>>>(Qb, Kb, Vtb, alibi, ctx_bf);
  cast_f32_bf16<<<16384, 256, 0, stream>>>(Wd, w_bf, 4194304);
  gemm_bt<1><<<dim3(32, 32), 256, 0, stream>>>(ctx_bf, w_bf, 4096, bd,
                                               resid, out, nullptr, nullptr, nullptr);
}